// Round 1
// baseline (265.006 us; speedup 1.0000x reference)
//
#include <hip/hip_runtime.h>
#include <math.h>

#define NQ 4096
#define CC 256
#define NHEAD 4
#define DHEAD 64
#define KNBR 64
#define NBATCH 2

// ---------------- GroupNorm stats: one block per (b,g), 64 blocks ----------
__global__ __launch_bounds__(256) void gn_stats_k(const float* __restrict__ x,
                                                  float* __restrict__ stats) {
    const int bg = blockIdx.x;  // b*32+g
    const float4* base = (const float4*)(x + (size_t)bg * 32768);
    float s = 0.f, ss = 0.f;
    for (int i = threadIdx.x; i < 8192; i += 256) {
        float4 v = base[i];
        s  += v.x + v.y + v.z + v.w;
        ss += v.x*v.x + v.y*v.y + v.z*v.z + v.w*v.w;
    }
    #pragma unroll
    for (int o = 32; o; o >>= 1) { s += __shfl_xor(s, o); ss += __shfl_xor(ss, o); }
    __shared__ float ls[4], lss[4];
    const int wv = threadIdx.x >> 6, ln = threadIdx.x & 63;
    if (ln == 0) { ls[wv] = s; lss[wv] = ss; }
    __syncthreads();
    if (threadIdx.x == 0) {
        float S  = ls[0] + ls[1] + ls[2] + ls[3];
        float SS = lss[0] + lss[1] + lss[2] + lss[3];
        float mean = S * (1.f / 32768.f);
        float var  = SS * (1.f / 32768.f) - mean * mean;
        stats[bg * 2]     = mean;
        stats[bg * 2 + 1] = rsqrtf(var + 1e-6f);
    }
}

// ---------------- GroupNorm apply: h = (x-mean)*rstd*sc + bi ---------------
__global__ __launch_bounds__(256) void gn_apply_k(const float* __restrict__ x,
                                                  const float* __restrict__ stats,
                                                  const float* __restrict__ sc,
                                                  const float* __restrict__ bi,
                                                  float* __restrict__ h) {
    const int i = blockIdx.x * 256 + threadIdx.x;  // float4 index, 524288 total
    const int e = i << 2;
    const int c  = (e >> 12) & 255;
    const int bg = e >> 15;
    const float mean = stats[bg * 2], rstd = stats[bg * 2 + 1];
    const float a  = rstd * sc[c];
    const float bb = bi[c] - mean * a;
    float4 v = ((const float4*)x)[i];
    float4 o = { v.x * a + bb, v.y * a + bb, v.z * a + bb, v.w * a + bb };
    ((float4*)h)[i] = o;
}

// ---------------- QKV GEMM: out[b,h,n,d] = W[h*64+d,:] @ hbuf[b,:,n] + bias -
// grid: (64 n-tiles, 4 heads, 6 = b*3+proj), block 256, 64x64 tile, 4x4 micro
__global__ __launch_bounds__(256) void qkv_gemm_k(const float* __restrict__ h,
        const float* __restrict__ wq, const float* __restrict__ bq,
        const float* __restrict__ wk, const float* __restrict__ bk,
        const float* __restrict__ wv, const float* __restrict__ bv,
        float* __restrict__ qt, float* __restrict__ kt, float* __restrict__ vt) {
    const int z = blockIdx.z;
    const int b = z / 3, p = z - b * 3;
    const float* W; const float* bias; float* out;
    if (p == 0)      { W = wq; bias = bq; out = qt; }
    else if (p == 1) { W = wk; bias = bk; out = kt; }
    else             { W = wv; bias = bv; out = vt; }
    const int hh = blockIdx.y;
    const int n0 = blockIdx.x * 64;
    const float* Bp = h + (size_t)b * CC * NQ;

    __shared__ float As[64][17];
    __shared__ float Bs[16][68];
    const int t = threadIdx.x;
    const int tx = t & 15, ty = t >> 4;
    const int ar = t >> 2,  aq  = (t & 3) << 2;
    const int br = t >> 4,  bqd = (t & 15) << 2;
    float acc[4][4] = {};

    for (int k0 = 0; k0 < CC; k0 += 16) {
        float4 av  = *(const float4*)(W  + (size_t)(hh * 64 + ar) * CC + k0 + aq);
        float4 bv4 = *(const float4*)(Bp + (size_t)(k0 + br) * NQ + n0 + bqd);
        As[ar][aq + 0] = av.x; As[ar][aq + 1] = av.y;
        As[ar][aq + 2] = av.z; As[ar][aq + 3] = av.w;
        *(float4*)&Bs[br][bqd] = bv4;
        __syncthreads();
        #pragma unroll
        for (int kc = 0; kc < 16; ++kc) {
            float a[4], bb[4];
            #pragma unroll
            for (int i = 0; i < 4; ++i) a[i] = As[ty * 4 + i][kc];
            #pragma unroll
            for (int j = 0; j < 4; ++j) bb[j] = Bs[kc][tx * 4 + j];
            #pragma unroll
            for (int i = 0; i < 4; ++i)
                #pragma unroll
                for (int j = 0; j < 4; ++j)
                    acc[i][j] += a[i] * bb[j];
        }
        __syncthreads();
    }
    const float b0 = bias[hh * 64 + ty * 4 + 0];
    const float b1 = bias[hh * 64 + ty * 4 + 1];
    const float b2 = bias[hh * 64 + ty * 4 + 2];
    const float b3 = bias[hh * 64 + ty * 4 + 3];
    // transposed write: out[((b*4+hh)*NQ + n)*64 + d]
    float* ob = out + ((size_t)(b * NHEAD + hh) * NQ + n0 + tx * 4) * 64 + ty * 4;
    #pragma unroll
    for (int j = 0; j < 4; ++j) {
        float4 v = { acc[0][j] + b0, acc[1][j] + b1, acc[2][j] + b2, acc[3][j] + b3 };
        *(float4*)(ob + (size_t)j * 64) = v;
    }
}

// ---------------- Attention: one wave per query, 4 queries/block -----------
__global__ __launch_bounds__(256) void attn_k(const float* __restrict__ qt,
        const float* __restrict__ kt, const float* __restrict__ vt,
        const int* __restrict__ aidx, const int* __restrict__ vmask,
        float* __restrict__ attnb) {
    const int blk = blockIdx.x;      // 8192 blocks
    const int q4 = blk & 1023;
    const int bh = blk >> 10;        // b*4+hh
    const int n0 = q4 * 4;
    const int wv = threadIdx.x >> 6, ln = threadIdx.x & 63;
    const int n = n0 + wv;

    const float* qbase = qt + ((size_t)bh * NQ + n) * 64;
    const float* kbase = kt + (size_t)bh * NQ * 64;
    const float* vbase = vt + (size_t)bh * NQ * 64;

    __shared__ float q_lds[4][64];
    __shared__ float o_lds[64][5];

    q_lds[wv][ln] = qbase[ln];
    const int idx = aidx[n * KNBR + ln];
    const int msk = vmask[n * KNBR + ln];
    __syncthreads();

    float dot = 0.f;
    if (msk) {
        const float4* krow = (const float4*)(kbase + (size_t)idx * 64);
        #pragma unroll
        for (int c4 = 0; c4 < 16; ++c4) {
            float4 kv = krow[c4];
            dot += kv.x * q_lds[wv][c4 * 4 + 0] + kv.y * q_lds[wv][c4 * 4 + 1]
                 + kv.z * q_lds[wv][c4 * 4 + 2] + kv.w * q_lds[wv][c4 * 4 + 3];
        }
    }
    float logit = msk ? dot : -INFINITY;
    float m = logit;
    #pragma unroll
    for (int o = 32; o; o >>= 1) m = fmaxf(m, __shfl_xor(m, o));
    float e = msk ? __expf(logit - m) : 0.f;
    float s = e;
    #pragma unroll
    for (int o = 32; o; o >>= 1) s += __shfl_xor(s, o);
    const float wgt = e / s;

    float acc = 0.f;
    for (int kk = 0; kk < 64; ++kk) {
        const float wk_ = __shfl(wgt, kk);   // wave-uniform
        if (wk_ != 0.f) {
            const int ik = __shfl(idx, kk);
            acc += wk_ * vbase[(size_t)ik * 64 + ln];
        }
    }

    // write attnbuf[b, c'=d*4+hh, n]  (reference channel permutation)
    o_lds[ln][wv] = acc;
    __syncthreads();
    if (wv == 0) {
        const int hh = bh & 3, b = bh >> 2;
        float4 v4 = { o_lds[ln][0], o_lds[ln][1], o_lds[ln][2], o_lds[ln][3] };
        *(float4*)(attnb + ((size_t)(b * CC + ln * 4 + hh)) * NQ + n0) = v4;
    }
}

// ---------------- Output GEMM + residual -----------------------------------
__global__ __launch_bounds__(256) void out_gemm_k(const float* __restrict__ attnb,
        const float* __restrict__ wo, const float* __restrict__ bo,
        const float* __restrict__ x, float* __restrict__ out) {
    const int b  = blockIdx.z;
    const int mt = blockIdx.y;
    const int n0 = blockIdx.x * 64;
    const float* Bp = attnb + (size_t)b * CC * NQ;

    __shared__ float As[64][17];
    __shared__ float Bs[16][68];
    const int t = threadIdx.x;
    const int tx = t & 15, ty = t >> 4;
    const int ar = t >> 2,  aq  = (t & 3) << 2;
    const int br = t >> 4,  bqd = (t & 15) << 2;
    float acc[4][4] = {};

    for (int k0 = 0; k0 < CC; k0 += 16) {
        float4 av  = *(const float4*)(wo + (size_t)(mt * 64 + ar) * CC + k0 + aq);
        float4 bv4 = *(const float4*)(Bp + (size_t)(k0 + br) * NQ + n0 + bqd);
        As[ar][aq + 0] = av.x; As[ar][aq + 1] = av.y;
        As[ar][aq + 2] = av.z; As[ar][aq + 3] = av.w;
        *(float4*)&Bs[br][bqd] = bv4;
        __syncthreads();
        #pragma unroll
        for (int kc = 0; kc < 16; ++kc) {
            float a[4], bb[4];
            #pragma unroll
            for (int i = 0; i < 4; ++i) a[i] = As[ty * 4 + i][kc];
            #pragma unroll
            for (int j = 0; j < 4; ++j) bb[j] = Bs[kc][tx * 4 + j];
            #pragma unroll
            for (int i = 0; i < 4; ++i)
                #pragma unroll
                for (int j = 0; j < 4; ++j)
                    acc[i][j] += a[i] * bb[j];
        }
        __syncthreads();
    }
    #pragma unroll
    for (int i = 0; i < 4; ++i) {
        const int o = mt * 64 + ty * 4 + i;
        const float bi = bo[o];
        const size_t addr = ((size_t)(b * CC + o)) * NQ + n0 + tx * 4;
        float4 xv = *(const float4*)(x + addr);
        float4 v = { acc[i][0] + bi + xv.x, acc[i][1] + bi + xv.y,
                     acc[i][2] + bi + xv.z, acc[i][3] + bi + xv.w };
        *(float4*)(out + addr) = v;
    }
}

extern "C" void kernel_launch(void* const* d_in, const int* in_sizes, int n_in,
                              void* d_out, int out_size, void* d_ws, size_t ws_size,
                              hipStream_t stream) {
    const float* x     = (const float*)d_in[0];
    const int*   vmask = (const int*)d_in[1];
    const int*   aidx  = (const int*)d_in[2];
    const float* gsc   = (const float*)d_in[3];
    const float* gbi   = (const float*)d_in[4];
    const float* wq    = (const float*)d_in[5];
    const float* bq    = (const float*)d_in[6];
    const float* wk    = (const float*)d_in[7];
    const float* bk    = (const float*)d_in[8];
    const float* wv    = (const float*)d_in[9];
    const float* bv    = (const float*)d_in[10];
    const float* wo    = (const float*)d_in[11];
    const float* bo    = (const float*)d_in[12];
    float* outp = (float*)d_out;

    float* f     = (float*)d_ws;
    float* stats = f;                  // 128 floats (pad to 1024)
    float* hbuf  = f + 1024;           // 2,097,152
    float* qt    = hbuf + 2097152;
    float* ktb   = qt   + 2097152;
    float* vtb   = ktb  + 2097152;
    float* attnb = vtb  + 2097152;     // total ~40 MB

    hipLaunchKernelGGL(gn_stats_k, dim3(64),        dim3(256), 0, stream, x, stats);
    hipLaunchKernelGGL(gn_apply_k, dim3(2048),      dim3(256), 0, stream, x, stats, gsc, gbi, hbuf);
    hipLaunchKernelGGL(qkv_gemm_k, dim3(64, 4, 6),  dim3(256), 0, stream,
                       hbuf, wq, bq, wk, bk, wv, bv, qt, ktb, vtb);
    hipLaunchKernelGGL(attn_k,     dim3(8192),      dim3(256), 0, stream,
                       qt, ktb, vtb, aidx, vmask, attnb);
    hipLaunchKernelGGL(out_gemm_k, dim3(64, 4, 2),  dim3(256), 0, stream,
                       attnb, wo, bo, x, outp);
}

// Round 2
// 195.025 us; speedup vs baseline: 1.3588x; 1.3588x over previous
//
#include <hip/hip_runtime.h>
#include <math.h>

typedef unsigned int uint;
typedef unsigned short ushort;
typedef __attribute__((ext_vector_type(8))) short bf16x8;
typedef __attribute__((ext_vector_type(4))) float f32x4;

#define LSTR 40   // LDS row stride in bf16 elems: 32 + 8 pad (80 B, 16B-aligned)

__device__ __forceinline__ float bf2f(ushort u) { return __uint_as_float(((uint)u) << 16); }
__device__ __forceinline__ ushort f2bf(float f) {
    uint u = __float_as_uint(f);
    return (ushort)((u + 0x7fffu + ((u >> 16) & 1u)) >> 16);  // RNE
}

// ---------------- GroupNorm partial sums: 256 blocks, atomics into stats ----
__global__ __launch_bounds__(256) void gn_part_k(const float* __restrict__ x,
                                                 float* __restrict__ stats) {
    const int bg = blockIdx.x >> 2, part = blockIdx.x & 3;
    const float4* base = (const float4*)(x + (size_t)bg * 32768 + part * 8192);
    float s = 0.f, ss = 0.f;
    for (int i = threadIdx.x; i < 2048; i += 256) {
        float4 v = base[i];
        s  += v.x + v.y + v.z + v.w;
        ss += v.x*v.x + v.y*v.y + v.z*v.z + v.w*v.w;
    }
    #pragma unroll
    for (int o = 32; o; o >>= 1) { s += __shfl_xor(s, o); ss += __shfl_xor(ss, o); }
    if ((threadIdx.x & 63) == 0) {
        atomicAdd(&stats[bg * 2],     s);
        atomicAdd(&stats[bg * 2 + 1], ss);
    }
}

// ------- GN apply + transpose: write hT[b][n][c] bf16 (64x64 tiles) ---------
__global__ __launch_bounds__(256) void gn_apply_t_k(const float* __restrict__ x,
        const float* __restrict__ stats, const float* __restrict__ sc,
        const float* __restrict__ bi, ushort* __restrict__ hT) {
    const int n0 = blockIdx.x * 64, c0 = blockIdx.y * 64, b = blockIdx.z;
    __shared__ ushort tile[64][65];
    const int t = threadIdx.x;
    // read phase: x[b][c0+r][n0 + 4*col4 ..], float4
    #pragma unroll
    for (int it = 0; it < 4; ++it) {
        const int r = (t >> 4) + it * 16, col4 = t & 15;
        const int c = c0 + r, bg = b * 32 + (c >> 3);
        const float S = stats[bg * 2], SS = stats[bg * 2 + 1];
        const float mean = S * (1.f / 32768.f);
        const float var  = SS * (1.f / 32768.f) - mean * mean;
        const float a  = rsqrtf(var + 1e-6f) * sc[c];
        const float bb = bi[c] - mean * a;
        float4 v = *(const float4*)(x + ((size_t)(b * 256 + c)) * 4096 + n0 + col4 * 4);
        tile[r][col4*4 + 0] = f2bf(v.x * a + bb);
        tile[r][col4*4 + 1] = f2bf(v.y * a + bb);
        tile[r][col4*4 + 2] = f2bf(v.z * a + bb);
        tile[r][col4*4 + 3] = f2bf(v.w * a + bb);
    }
    __syncthreads();
    // write phase: hT[b][n0+nr][c0 + 8*c8 ..], 16B per thread
    #pragma unroll
    for (int it = 0; it < 2; ++it) {
        const int nr = (t >> 3) + it * 32, c8 = t & 7;
        uint4 st;
        ushort e0 = tile[c8*8+0][nr], e1 = tile[c8*8+1][nr];
        ushort e2 = tile[c8*8+2][nr], e3 = tile[c8*8+3][nr];
        ushort e4 = tile[c8*8+4][nr], e5 = tile[c8*8+5][nr];
        ushort e6 = tile[c8*8+6][nr], e7 = tile[c8*8+7][nr];
        st.x = (uint)e0 | ((uint)e1 << 16);
        st.y = (uint)e2 | ((uint)e3 << 16);
        st.z = (uint)e4 | ((uint)e5 << 16);
        st.w = (uint)e6 | ((uint)e7 << 16);
        *(uint4*)(hT + ((size_t)b * 4096 + n0 + nr) * 256 + c0 + c8 * 8) = st;
    }
}

// ---------------- Weight prep: bf16 casts, wo column-permute, bias pack -----
__global__ __launch_bounds__(256) void wprep_k(
        const float* __restrict__ wq, const float* __restrict__ wk,
        const float* __restrict__ wv, const float* __restrict__ wo,
        const float* __restrict__ bq, const float* __restrict__ bk,
        const float* __restrict__ bv,
        ushort* __restrict__ wqkv, ushort* __restrict__ wo_p,
        float* __restrict__ bqkv) {
    const int i = blockIdx.x * 256 + threadIdx.x;
    if (i < 196608) {               // wqkv[768][256]
        const int o = i >> 8, k = i & 255;
        const float* W = (o < 256) ? wq : ((o < 512) ? wk : wv);
        wqkv[i] = f2bf(W[(o & 255) * 256 + k]);
    } else if (i < 262144) {        // wo_p[o][h*64+d] = wo[o][d*4+h]
        const int j = i - 196608;
        const int o = j >> 8, kp = j & 255;
        const int h = kp >> 6, d = kp & 63;
        wo_p[j] = f2bf(wo[o * 256 + d * 4 + h]);
    } else if (i < 262912) {        // bqkv[768]
        const int o = i - 262144;
        bqkv[o] = (o < 256) ? bq[o] : ((o < 512) ? bk[o - 256] : bv[o - 512]);
    }
}

// ---------------- QKV GEMM (MFMA bf16): [768,256]@[256,4096] per batch ------
// grid (32 n-tiles, 6 m-tiles, 2 b), 256 thr, 128x128 tile, 4 waves 2x2
__global__ __launch_bounds__(256) void qkv_gemm_k(
        const ushort* __restrict__ Wqkv, const float* __restrict__ bqkv,
        const ushort* __restrict__ hT, ushort* __restrict__ qkvb) {
    const int nt = blockIdx.x, mt = blockIdx.y, b = blockIdx.z;
    __shared__ ushort As[128 * LSTR];
    __shared__ ushort Bs[128 * LSTR];
    const int t = threadIdx.x;
    const int wave = t >> 6, ln = t & 63;
    const int wm = wave >> 1, wn = wave & 1;
    f32x4 acc[4][4] = {};
    const ushort* Ag = Wqkv + (size_t)(mt * 128) * 256;
    const ushort* Bg = hT + ((size_t)b * 4096 + nt * 128) * 256;
    const int srow = t >> 2, sc8 = (t & 3) * 8;
    const int fr = ln & 15, kA = (ln >> 4) * 8;

    for (int k0 = 0; k0 < 256; k0 += 32) {
        #pragma unroll
        for (int i = 0; i < 2; ++i) {
            const int row = srow + i * 64;
            *(uint4*)&As[row * LSTR + sc8] = *(const uint4*)&Ag[(size_t)row * 256 + k0 + sc8];
            *(uint4*)&Bs[row * LSTR + sc8] = *(const uint4*)&Bg[(size_t)row * 256 + k0 + sc8];
        }
        __syncthreads();
        bf16x8 af[4], bfr[4];
        #pragma unroll
        for (int m = 0; m < 4; ++m) af[m]  = *(bf16x8*)&As[(wm * 64 + m * 16 + fr) * LSTR + kA];
        #pragma unroll
        for (int n = 0; n < 4; ++n) bfr[n] = *(bf16x8*)&Bs[(wn * 64 + n * 16 + fr) * LSTR + kA];
        #pragma unroll
        for (int m = 0; m < 4; ++m)
            #pragma unroll
            for (int n = 0; n < 4; ++n)
                acc[m][n] = __builtin_amdgcn_mfma_f32_16x16x32_bf16(af[m], bfr[n], acc[m][n], 0, 0, 0);
        __syncthreads();
    }
    // epilogue: write q/k/v as bf16 [proj][b*4+head][n][d]
    const int colb = nt * 128 + wn * 64 + fr;
    const int rowb = mt * 128 + wm * 64;
    #pragma unroll
    for (int m = 0; m < 4; ++m) {
        const int o0 = rowb + m * 16 + ((ln >> 4) << 2);
        const int proj = o0 >> 8;
        const int head = (o0 >> 6) & 3;
        const int d0 = o0 & 63;
        const float4 bi4 = *(const float4*)&bqkv[o0];
        ushort* obase = qkvb + ((size_t)proj * 8 + (b * 4 + head)) * (4096 * 64) + d0;
        #pragma unroll
        for (int n = 0; n < 4; ++n) {
            const int nn = colb + n * 16;
            f32x4 a = acc[m][n];
            uint2 st;
            st.x = (uint)f2bf(a[0] + bi4.x) | ((uint)f2bf(a[1] + bi4.y) << 16);
            st.y = (uint)f2bf(a[2] + bi4.z) | ((uint)f2bf(a[3] + bi4.w) << 16);
            *(uint2*)&obase[(size_t)nn * 64] = st;
        }
    }
}

// ---------------- Attention: 4 waves = 4 queries/block, bf16 K/V ------------
__global__ __launch_bounds__(256) void attn_k(
        const ushort* __restrict__ qb, const ushort* __restrict__ kb,
        const ushort* __restrict__ vb, const int* __restrict__ aidx,
        const int* __restrict__ vmask, ushort* __restrict__ attnb) {
    const int bh = blockIdx.x & 7;       // XCD-affinity: bid%8 == bh
    const int q4 = blockIdx.x >> 3;
    const int wave = threadIdx.x >> 6, ln = threadIdx.x & 63;
    const int n = q4 * 4 + wave;
    const ushort* kbase = kb + (size_t)bh * (4096 * 64);
    const ushort* vbase = vb + (size_t)bh * (4096 * 64);
    __shared__ float q_lds[4][64];
    q_lds[wave][ln] = bf2f(qb[(size_t)bh * (4096 * 64) + (size_t)n * 64 + ln]);
    const int idx = aidx[n * 64 + ln];
    const int msk = vmask[n * 64 + ln];
    __syncthreads();

    float dot = 0.f;
    if (msk) {
        const uint4* krow = (const uint4*)(kbase + (size_t)idx * 64);
        const float* qv = q_lds[wave];
        #pragma unroll
        for (int c = 0; c < 8; ++c) {
            uint4 u = krow[c];
            dot += __uint_as_float(u.x << 16)         * qv[c*8+0];
            dot += __uint_as_float(u.x & 0xffff0000u) * qv[c*8+1];
            dot += __uint_as_float(u.y << 16)         * qv[c*8+2];
            dot += __uint_as_float(u.y & 0xffff0000u) * qv[c*8+3];
            dot += __uint_as_float(u.z << 16)         * qv[c*8+4];
            dot += __uint_as_float(u.z & 0xffff0000u) * qv[c*8+5];
            dot += __uint_as_float(u.w << 16)         * qv[c*8+6];
            dot += __uint_as_float(u.w & 0xffff0000u) * qv[c*8+7];
        }
    }
    float mx = msk ? dot : -1e30f;
    #pragma unroll
    for (int o = 32; o; o >>= 1) mx = fmaxf(mx, __shfl_xor(mx, o));
    float e = msk ? __expf(dot - mx) : 0.f;
    float s = e;
    #pragma unroll
    for (int o = 32; o; o >>= 1) s += __shfl_xor(s, o);
    const float wgt = e / s;

    // branch-free, unrolled PV: 64 independent bf16 loads, 4 acc chains
    float a0 = 0.f, a1 = 0.f, a2 = 0.f, a3 = 0.f;
    #pragma unroll
    for (int kk = 0; kk < 64; kk += 4) {
        const float w0 = __shfl(wgt, kk),     w1 = __shfl(wgt, kk + 1);
        const float w2 = __shfl(wgt, kk + 2), w3 = __shfl(wgt, kk + 3);
        const int i0 = __shfl(idx, kk),     i1 = __shfl(idx, kk + 1);
        const int i2 = __shfl(idx, kk + 2), i3 = __shfl(idx, kk + 3);
        a0 += w0 * bf2f(vbase[(size_t)i0 * 64 + ln]);
        a1 += w1 * bf2f(vbase[(size_t)i1 * 64 + ln]);
        a2 += w2 * bf2f(vbase[(size_t)i2 * 64 + ln]);
        a3 += w3 * bf2f(vbase[(size_t)i3 * 64 + ln]);
    }
    const int b = bh >> 2, h = bh & 3;
    attnb[((size_t)b * 4096 + n) * 256 + h * 64 + ln] = f2bf(a0 + a1 + a2 + a3);
}

// ---------------- Output GEMM (MFMA) + bias + residual ----------------------
// grid (32 n-tiles, 2 m-tiles, 2 b)
__global__ __launch_bounds__(256) void out_gemm_k(
        const ushort* __restrict__ wo_p, const float* __restrict__ bo,
        const ushort* __restrict__ attnb, const float* __restrict__ x,
        float* __restrict__ outp) {
    const int nt = blockIdx.x, mt = blockIdx.y, b = blockIdx.z;
    __shared__ ushort As[128 * LSTR];
    __shared__ ushort Bs[128 * LSTR];
    const int t = threadIdx.x;
    const int wave = t >> 6, ln = t & 63;
    const int wm = wave >> 1, wn = wave & 1;
    f32x4 acc[4][4] = {};
    const ushort* Ag = wo_p + (size_t)(mt * 128) * 256;
    const ushort* Bg = attnb + ((size_t)b * 4096 + nt * 128) * 256;
    const int srow = t >> 2, sc8 = (t & 3) * 8;
    const int fr = ln & 15, kA = (ln >> 4) * 8;

    for (int k0 = 0; k0 < 256; k0 += 32) {
        #pragma unroll
        for (int i = 0; i < 2; ++i) {
            const int row = srow + i * 64;
            *(uint4*)&As[row * LSTR + sc8] = *(const uint4*)&Ag[(size_t)row * 256 + k0 + sc8];
            *(uint4*)&Bs[row * LSTR + sc8] = *(const uint4*)&Bg[(size_t)row * 256 + k0 + sc8];
        }
        __syncthreads();
        bf16x8 af[4], bfr[4];
        #pragma unroll
        for (int m = 0; m < 4; ++m) af[m]  = *(bf16x8*)&As[(wm * 64 + m * 16 + fr) * LSTR + kA];
        #pragma unroll
        for (int n = 0; n < 4; ++n) bfr[n] = *(bf16x8*)&Bs[(wn * 64 + n * 16 + fr) * LSTR + kA];
        #pragma unroll
        for (int m = 0; m < 4; ++m)
            #pragma unroll
            for (int n = 0; n < 4; ++n)
                acc[m][n] = __builtin_amdgcn_mfma_f32_16x16x32_bf16(af[m], bfr[n], acc[m][n], 0, 0, 0);
        __syncthreads();
    }
    const int colb = nt * 128 + wn * 64 + fr;
    const int rowb = mt * 128 + wm * 64;
    #pragma unroll
    for (int m = 0; m < 4; ++m) {
        const int o0 = rowb + m * 16 + ((ln >> 4) << 2);
        const float4 bi4 = *(const float4*)&bo[o0];
        const float* bip = (const float*)&bi4;
        #pragma unroll
        for (int n = 0; n < 4; ++n) {
            const int nn = colb + n * 16;
            #pragma unroll
            for (int r = 0; r < 4; ++r) {
                const size_t a = ((size_t)(b * 256 + o0 + r)) * 4096 + nn;
                outp[a] = acc[m][n][r] + bip[r] + x[a];
            }
        }
    }
}

extern "C" void kernel_launch(void* const* d_in, const int* in_sizes, int n_in,
                              void* d_out, int out_size, void* d_ws, size_t ws_size,
                              hipStream_t stream) {
    const float* x     = (const float*)d_in[0];
    const int*   vmask = (const int*)d_in[1];
    const int*   aidx  = (const int*)d_in[2];
    const float* gsc   = (const float*)d_in[3];
    const float* gbi   = (const float*)d_in[4];
    const float* wq    = (const float*)d_in[5];
    const float* bq    = (const float*)d_in[6];
    const float* wk    = (const float*)d_in[7];
    const float* bk    = (const float*)d_in[8];
    const float* wv    = (const float*)d_in[9];
    const float* bv    = (const float*)d_in[10];
    const float* wo    = (const float*)d_in[11];
    const float* bo    = (const float*)d_in[12];
    float* outp = (float*)d_out;

    char* w = (char*)d_ws;
    float*  stats = (float*)w;                          // 512 B
    ushort* wqkv  = (ushort*)(w + 1024);                // 393216 B
    ushort* wo_p  = (ushort*)(w + 1024 + 393216);       // 131072 B
    float*  bqkv  = (float*)(w + 525312);               // 3072 B
    ushort* hT    = (ushort*)(w + 528384);              // 4 MB
    ushort* qkvb  = (ushort*)(w + 4722688);             // 12 MB (q,k,v)
    ushort* attnb = (ushort*)(w + 17305600);            // 4 MB

    ushort* qbuf = qkvb;
    ushort* kbuf = qkvb + 2097152;
    ushort* vbuf = qkvb + 4194304;

    hipMemsetAsync(stats, 0, 512, stream);
    hipLaunchKernelGGL(gn_part_k,    dim3(256),        dim3(256), 0, stream, x, stats);
    hipLaunchKernelGGL(wprep_k,      dim3(1027),       dim3(256), 0, stream,
                       wq, wk, wv, wo, bq, bk, bv, wqkv, wo_p, bqkv);
    hipLaunchKernelGGL(gn_apply_t_k, dim3(64, 4, 2),   dim3(256), 0, stream,
                       x, stats, gsc, gbi, hT);
    hipLaunchKernelGGL(qkv_gemm_k,   dim3(32, 6, 2),   dim3(256), 0, stream,
                       wqkv, bqkv, hT, qkvb);
    hipLaunchKernelGGL(attn_k,       dim3(8192),       dim3(256), 0, stream,
                       qbuf, kbuf, vbuf, aidx, vmask, attnb);
    hipLaunchKernelGGL(out_gemm_k,   dim3(32, 2, 2),   dim3(256), 0, stream,
                       wo_p, bo, attnb, x, outp);
}

// Round 7
// 173.371 us; speedup vs baseline: 1.5285x; 1.1249x over previous
//
#include <hip/hip_runtime.h>
#include <math.h>

typedef unsigned int uint;
typedef unsigned short ushort;
typedef __attribute__((ext_vector_type(8))) short bf16x8;
typedef __attribute__((ext_vector_type(4))) float f32x4;

#define LSTR 40   // LDS row stride in bf16 elems: 32 + 8 pad (80 B, 16B-aligned)

__device__ __forceinline__ float bf2f(ushort u) { return __uint_as_float(((uint)u) << 16); }
__device__ __forceinline__ ushort f2bf(float f) {
    uint u = __float_as_uint(f);
    return (ushort)((u + 0x7fffu + ((u >> 16) & 1u)) >> 16);  // RNE
}
__device__ __forceinline__ int   RLI(int v, int l)   { return __builtin_amdgcn_readlane(v, l); }
__device__ __forceinline__ float RLF(float v, int l) {
    return __int_as_float(__builtin_amdgcn_readlane(__float_as_int(v), l));
}

// ---------------- GroupNorm partial sums: 256 blocks, atomics into stats ----
__global__ __launch_bounds__(256) void gn_part_k(const float* __restrict__ x,
                                                 float* __restrict__ stats) {
    const int bg = blockIdx.x >> 2, part = blockIdx.x & 3;
    const float4* base = (const float4*)(x + (size_t)bg * 32768 + part * 8192);
    float s = 0.f, ss = 0.f;
    for (int i = threadIdx.x; i < 2048; i += 256) {
        float4 v = base[i];
        s  += v.x + v.y + v.z + v.w;
        ss += v.x*v.x + v.y*v.y + v.z*v.z + v.w*v.w;
    }
    #pragma unroll
    for (int o = 32; o; o >>= 1) { s += __shfl_xor(s, o); ss += __shfl_xor(ss, o); }
    if ((threadIdx.x & 63) == 0) {
        atomicAdd(&stats[bg * 2],     s);
        atomicAdd(&stats[bg * 2 + 1], ss);
    }
}

// ------- GN apply + transpose: write hT[b][n][c] bf16 (64x64 tiles) ---------
__global__ __launch_bounds__(256) void gn_apply_t_k(const float* __restrict__ x,
        const float* __restrict__ stats, const float* __restrict__ sc,
        const float* __restrict__ bi, ushort* __restrict__ hT) {
    const int n0 = blockIdx.x * 64, c0 = blockIdx.y * 64, b = blockIdx.z;
    __shared__ ushort tile[64][65];
    const int t = threadIdx.x;
    #pragma unroll
    for (int it = 0; it < 4; ++it) {
        const int r = (t >> 4) + it * 16, col4 = t & 15;
        const int c = c0 + r, bg = b * 32 + (c >> 3);
        const float S = stats[bg * 2], SS = stats[bg * 2 + 1];
        const float mean = S * (1.f / 32768.f);
        const float var  = SS * (1.f / 32768.f) - mean * mean;
        const float a  = rsqrtf(var + 1e-6f) * sc[c];
        const float bb = bi[c] - mean * a;
        float4 v = *(const float4*)(x + ((size_t)(b * 256 + c)) * 4096 + n0 + col4 * 4);
        tile[r][col4*4 + 0] = f2bf(v.x * a + bb);
        tile[r][col4*4 + 1] = f2bf(v.y * a + bb);
        tile[r][col4*4 + 2] = f2bf(v.z * a + bb);
        tile[r][col4*4 + 3] = f2bf(v.w * a + bb);
    }
    __syncthreads();
    #pragma unroll
    for (int it = 0; it < 2; ++it) {
        const int nr = (t >> 3) + it * 32, c8 = t & 7;
        uint4 st;
        ushort e0 = tile[c8*8+0][nr], e1 = tile[c8*8+1][nr];
        ushort e2 = tile[c8*8+2][nr], e3 = tile[c8*8+3][nr];
        ushort e4 = tile[c8*8+4][nr], e5 = tile[c8*8+5][nr];
        ushort e6 = tile[c8*8+6][nr], e7 = tile[c8*8+7][nr];
        st.x = (uint)e0 | ((uint)e1 << 16);
        st.y = (uint)e2 | ((uint)e3 << 16);
        st.z = (uint)e4 | ((uint)e5 << 16);
        st.w = (uint)e6 | ((uint)e7 << 16);
        *(uint4*)(hT + ((size_t)b * 4096 + n0 + nr) * 256 + c0 + c8 * 8) = st;
    }
}

// ---------------- Weight prep: bf16 casts, wo column-permute, bias pack -----
__global__ __launch_bounds__(256) void wprep_k(
        const float* __restrict__ wq, const float* __restrict__ wk,
        const float* __restrict__ wv, const float* __restrict__ wo,
        const float* __restrict__ bq, const float* __restrict__ bk,
        const float* __restrict__ bv,
        ushort* __restrict__ wqkv, ushort* __restrict__ wo_p,
        float* __restrict__ bqkv) {
    const int i = blockIdx.x * 256 + threadIdx.x;
    if (i < 196608) {               // wqkv[768][256]
        const int o = i >> 8, k = i & 255;
        const float* W = (o < 256) ? wq : ((o < 512) ? wk : wv);
        wqkv[i] = f2bf(W[(o & 255) * 256 + k]);
    } else if (i < 262144) {        // wo_p[o][h*64+d] = wo[o][d*4+h]
        const int j = i - 196608;
        const int o = j >> 8, kp = j & 255;
        const int h = kp >> 6, d = kp & 63;
        wo_p[j] = f2bf(wo[o * 256 + d * 4 + h]);
    } else if (i < 262912) {        // bqkv[768]
        const int o = i - 262144;
        bqkv[o] = (o < 256) ? bq[o] : ((o < 512) ? bk[o - 256] : bv[o - 512]);
    }
}

// ---------------- QKV GEMM (MFMA bf16): 128x64 tiles, grid (64,6,2) ---------
// Q rows written as f32 to qf; K/V rows as bf16 to kvb.
__global__ __launch_bounds__(256) void qkv_gemm_k(
        const ushort* __restrict__ Wqkv, const float* __restrict__ bqkv,
        const ushort* __restrict__ hT, float* __restrict__ qf,
        ushort* __restrict__ kvb) {
    const int nt = blockIdx.x, mt = blockIdx.y, b = blockIdx.z;
    __shared__ ushort As[128 * LSTR];
    __shared__ ushort Bs[64 * LSTR];
    const int t = threadIdx.x;
    const int wave = t >> 6, ln = t & 63;
    const int wm = wave >> 1, wn = wave & 1;
    f32x4 acc[4][2] = {};
    const ushort* Ag = Wqkv + (size_t)(mt * 128) * 256;
    const ushort* Bg = hT + ((size_t)b * 4096 + nt * 64) * 256;
    const int srow = t >> 2, sc8 = (t & 3) * 8;
    const int fr = ln & 15, kA = (ln >> 4) * 8;

    for (int k0 = 0; k0 < 256; k0 += 32) {
        *(uint4*)&As[srow * LSTR + sc8]        = *(const uint4*)&Ag[(size_t)srow * 256 + k0 + sc8];
        *(uint4*)&As[(srow + 64) * LSTR + sc8] = *(const uint4*)&Ag[(size_t)(srow + 64) * 256 + k0 + sc8];
        *(uint4*)&Bs[srow * LSTR + sc8]        = *(const uint4*)&Bg[(size_t)srow * 256 + k0 + sc8];
        __syncthreads();
        bf16x8 af[4], bfr[2];
        #pragma unroll
        for (int m = 0; m < 4; ++m) af[m]  = *(bf16x8*)&As[(wm * 64 + m * 16 + fr) * LSTR + kA];
        #pragma unroll
        for (int n = 0; n < 2; ++n) bfr[n] = *(bf16x8*)&Bs[(wn * 32 + n * 16 + fr) * LSTR + kA];
        #pragma unroll
        for (int m = 0; m < 4; ++m)
            #pragma unroll
            for (int n = 0; n < 2; ++n)
                acc[m][n] = __builtin_amdgcn_mfma_f32_16x16x32_bf16(af[m], bfr[n], acc[m][n], 0, 0, 0);
        __syncthreads();
    }
    const int colb = nt * 64 + wn * 32 + fr;
    const int rowb = mt * 128 + wm * 64;
    #pragma unroll
    for (int m = 0; m < 4; ++m) {
        const int o0 = rowb + m * 16 + ((ln >> 4) << 2);
        const int proj = o0 >> 8;          // wave-uniform (64-chunk within one proj)
        const int head = (o0 >> 6) & 3;
        const int d0 = o0 & 63;
        const float4 bi4 = *(const float4*)&bqkv[o0];
        if (proj == 0) {
            float* obase = qf + ((size_t)(b * 4 + head) * 4096) * 64 + d0;
            #pragma unroll
            for (int n = 0; n < 2; ++n) {
                const int nn = colb + n * 16;
                f32x4 a = acc[m][n];
                float4 st = { a[0] + bi4.x, a[1] + bi4.y, a[2] + bi4.z, a[3] + bi4.w };
                *(float4*)&obase[(size_t)nn * 64] = st;
            }
        } else {
            ushort* obase = kvb + ((size_t)(proj - 1) * 8 + (b * 4 + head)) * (4096 * 64) + d0;
            #pragma unroll
            for (int n = 0; n < 2; ++n) {
                const int nn = colb + n * 16;
                f32x4 a = acc[m][n];
                uint2 st;
                st.x = (uint)f2bf(a[0] + bi4.x) | ((uint)f2bf(a[1] + bi4.y) << 16);
                st.y = (uint)f2bf(a[2] + bi4.z) | ((uint)f2bf(a[3] + bi4.w) << 16);
                *(uint2*)&obase[(size_t)nn * 64] = st;
            }
        }
    }
}

// ---------------- Attention: LDS-free, branch-free, f32 Q -------------------
__global__ __launch_bounds__(256) void attn_k(
        const float* __restrict__ qf, const ushort* __restrict__ kb,
        const ushort* __restrict__ vb, const int* __restrict__ aidx,
        const int* __restrict__ vmask, ushort* __restrict__ attnb) {
    const int bh = blockIdx.x & 7;       // XCD-affinity
    const int q4 = blockIdx.x >> 3;
    const int wave = threadIdx.x >> 6, ln = threadIdx.x & 63;
    const int n = q4 * 4 + wave;
    const ushort* kbase = kb + (size_t)bh * (4096 * 64);
    const ushort* vbase = vb + (size_t)bh * (4096 * 64);
    const float qreg = qf[((size_t)bh * 4096 + n) * 64 + ln];
    const int idx = aidx[n * 64 + ln];
    const int msk = vmask[n * 64 + ln];

    // --- QK: lane ln owns neighbor ln (branch-free; masked lanes gather too)
    float d0 = 0.f, d1 = 0.f, d2 = 0.f, d3 = 0.f;
    {
        const uint4* krow = (const uint4*)(kbase + (size_t)idx * 64);
        #pragma unroll
        for (int c = 0; c < 8; ++c) {
            uint4 u = krow[c];
            d0 += __uint_as_float(u.x << 16)         * RLF(qreg, c*8 + 0);
            d1 += __uint_as_float(u.x & 0xffff0000u) * RLF(qreg, c*8 + 1);
            d2 += __uint_as_float(u.y << 16)         * RLF(qreg, c*8 + 2);
            d3 += __uint_as_float(u.y & 0xffff0000u) * RLF(qreg, c*8 + 3);
            d0 += __uint_as_float(u.z << 16)         * RLF(qreg, c*8 + 4);
            d1 += __uint_as_float(u.z & 0xffff0000u) * RLF(qreg, c*8 + 5);
            d2 += __uint_as_float(u.w << 16)         * RLF(qreg, c*8 + 6);
            d3 += __uint_as_float(u.w & 0xffff0000u) * RLF(qreg, c*8 + 7);
        }
    }
    const float dot = (d0 + d1) + (d2 + d3);
    float mx = msk ? dot : -1e30f;
    #pragma unroll
    for (int o = 32; o; o >>= 1) mx = fmaxf(mx, __shfl_xor(mx, o));
    const float e = msk ? __expf(dot - mx) : 0.f;
    float s = e;
    #pragma unroll
    for (int o = 32; o; o >>= 1) s += __shfl_xor(s, o);
    const float wgt = e / s;

    // --- PV: 4 neighbors/iter; 16-lane group p owns neighbor 4k+p -----------
    const int p = ln >> 4, d4 = ln & 15;
    const bool c1 = (p == 1), c2 = (p == 2), c3 = (p == 3);
    float a0 = 0.f, a1 = 0.f, a2 = 0.f, a3 = 0.f;
    const ushort* vb2 = vbase + d4 * 4;
    #pragma unroll
    for (int k = 0; k < 64; k += 4) {
        const int   i0 = RLI(idx, k),     i1 = RLI(idx, k + 1);
        const int   i2 = RLI(idx, k + 2), i3 = RLI(idx, k + 3);
        const float w0 = RLF(wgt, k),     w1 = RLF(wgt, k + 1);
        const float w2 = RLF(wgt, k + 2), w3 = RLF(wgt, k + 3);
        int   si = c1 ? i1 : i0; si = c2 ? i2 : si; si = c3 ? i3 : si;
        float sw = c1 ? w1 : w0; sw = c2 ? w2 : sw; sw = c3 ? w3 : sw;
        const uint2 u = *(const uint2*)(vb2 + (size_t)si * 64);
        a0 += sw * __uint_as_float(u.x << 16);
        a1 += sw * __uint_as_float(u.x & 0xffff0000u);
        a2 += sw * __uint_as_float(u.y << 16);
        a3 += sw * __uint_as_float(u.y & 0xffff0000u);
    }
    #pragma unroll
    for (int o = 16; o <= 32; o <<= 1) {
        a0 += __shfl_xor(a0, o); a1 += __shfl_xor(a1, o);
        a2 += __shfl_xor(a2, o); a3 += __shfl_xor(a3, o);
    }
    if (p == 0) {
        const int b = bh >> 2, h = bh & 3;
        uint2 st;
        st.x = (uint)f2bf(a0) | ((uint)f2bf(a1) << 16);
        st.y = (uint)f2bf(a2) | ((uint)f2bf(a3) << 16);
        *(uint2*)(attnb + ((size_t)b * 4096 + n) * 256 + h * 64 + d4 * 4) = st;
    }
}

// ---------------- Output GEMM (MFMA): 64x64 tiles, grid (64,4,2) ------------
__global__ __launch_bounds__(256) void out_gemm_k(
        const ushort* __restrict__ wo_p, const float* __restrict__ bo,
        const ushort* __restrict__ attnb, const float* __restrict__ x,
        float* __restrict__ outp) {
    const int nt = blockIdx.x, mt = blockIdx.y, b = blockIdx.z;
    __shared__ ushort As[64 * LSTR];
    __shared__ ushort Bs[64 * LSTR];
    const int t = threadIdx.x;
    const int wave = t >> 6, ln = t & 63;
    const int wm = wave >> 1, wn = wave & 1;
    f32x4 acc[2][2] = {};
    const ushort* Ag = wo_p + (size_t)(mt * 64) * 256;
    const ushort* Bg = attnb + ((size_t)b * 4096 + nt * 64) * 256;
    const int srow = t >> 2, sc8 = (t & 3) * 8;
    const int fr = ln & 15, kA = (ln >> 4) * 8;

    for (int k0 = 0; k0 < 256; k0 += 32) {
        *(uint4*)&As[srow * LSTR + sc8] = *(const uint4*)&Ag[(size_t)srow * 256 + k0 + sc8];
        *(uint4*)&Bs[srow * LSTR + sc8] = *(const uint4*)&Bg[(size_t)srow * 256 + k0 + sc8];
        __syncthreads();
        bf16x8 af[2], bfr[2];
        #pragma unroll
        for (int m = 0; m < 2; ++m) af[m]  = *(bf16x8*)&As[(wm * 32 + m * 16 + fr) * LSTR + kA];
        #pragma unroll
        for (int n = 0; n < 2; ++n) bfr[n] = *(bf16x8*)&Bs[(wn * 32 + n * 16 + fr) * LSTR + kA];
        #pragma unroll
        for (int m = 0; m < 2; ++m)
            #pragma unroll
            for (int n = 0; n < 2; ++n)
                acc[m][n] = __builtin_amdgcn_mfma_f32_16x16x32_bf16(af[m], bfr[n], acc[m][n], 0, 0, 0);
        __syncthreads();
    }
    const int colb = nt * 64 + wn * 32 + fr;
    const int rowb = mt * 64 + wm * 32;
    #pragma unroll
    for (int m = 0; m < 2; ++m) {
        const int o0 = rowb + m * 16 + ((ln >> 4) << 2);
        const float4 bi4 = *(const float4*)&bo[o0];
        const float* bip = (const float*)&bi4;
        #pragma unroll
        for (int n = 0; n < 2; ++n) {
            const int nn = colb + n * 16;
            #pragma unroll
            for (int r = 0; r < 4; ++r) {
                const size_t a = ((size_t)(b * 256 + o0 + r)) * 4096 + nn;
                outp[a] = acc[m][n][r] + bip[r] + x[a];
            }
        }
    }
}

extern "C" void kernel_launch(void* const* d_in, const int* in_sizes, int n_in,
                              void* d_out, int out_size, void* d_ws, size_t ws_size,
                              hipStream_t stream) {
    const float* x     = (const float*)d_in[0];
    const int*   vmask = (const int*)d_in[1];
    const int*   aidx  = (const int*)d_in[2];
    const float* gsc   = (const float*)d_in[3];
    const float* gbi   = (const float*)d_in[4];
    const float* wq    = (const float*)d_in[5];
    const float* bq    = (const float*)d_in[6];
    const float* wk    = (const float*)d_in[7];
    const float* bk    = (const float*)d_in[8];
    const float* wv    = (const float*)d_in[9];
    const float* bv    = (const float*)d_in[10];
    const float* wo    = (const float*)d_in[11];
    const float* bo    = (const float*)d_in[12];
    float* outp = (float*)d_out;

    char* w = (char*)d_ws;
    float*  stats = (float*)w;                          // 512 B (pad 1024)
    ushort* wqkv  = (ushort*)(w + 1024);                // 393216 B
    ushort* wo_p  = (ushort*)(w + 394240);              // 131072 B
    float*  bqkv  = (float*)(w + 525312);               // 3072 B
    ushort* hT    = (ushort*)(w + 528384);              // 4 MB
    float*  qf    = (float*)(w + 4722688);              // 8 MB f32 Q
    ushort* kvb   = (ushort*)(w + 13111296);            // 8 MB (K,V bf16)
    ushort* attnb = (ushort*)(w + 21499904);            // 4 MB

    ushort* kbuf = kvb;
    ushort* vbuf = kvb + 2097152;

    hipMemsetAsync(stats, 0, 512, stream);
    hipLaunchKernelGGL(gn_part_k,    dim3(256),        dim3(256), 0, stream, x, stats);
    hipLaunchKernelGGL(wprep_k,      dim3(1027),       dim3(256), 0, stream,
                       wq, wk, wv, wo, bq, bk, bv, wqkv, wo_p, bqkv);
    hipLaunchKernelGGL(gn_apply_t_k, dim3(64, 4, 2),   dim3(256), 0, stream,
                       x, stats, gsc, gbi, hT);
    hipLaunchKernelGGL(qkv_gemm_k,   dim3(64, 6, 2),   dim3(256), 0, stream,
                       wqkv, bqkv, hT, qf, kvb);
    hipLaunchKernelGGL(attn_k,       dim3(8192),       dim3(256), 0, stream,
                       qf, kbuf, vbuf, aidx, vmask, attnb);
    hipLaunchKernelGGL(out_gemm_k,   dim3(64, 4, 2),   dim3(256), 0, stream,
                       wo_p, bo, attnb, x, outp);
}

// Round 8
// 169.348 us; speedup vs baseline: 1.5649x; 1.0238x over previous
//
#include <hip/hip_runtime.h>
#include <math.h>

typedef unsigned int uint;
typedef unsigned short ushort;
typedef __attribute__((ext_vector_type(8))) short bf16x8;
typedef __attribute__((ext_vector_type(4))) float f32x4;

#define LSTR 40   // LDS row stride in bf16 elems: 32 + 8 pad (80 B, 16B-aligned)

__device__ __forceinline__ float bf2f(ushort u) { return __uint_as_float(((uint)u) << 16); }
__device__ __forceinline__ ushort f2bf(float f) {
    uint u = __float_as_uint(f);
    return (ushort)((u + 0x7fffu + ((u >> 16) & 1u)) >> 16);  // RNE
}

// ---------------- GroupNorm partial sums: 256 blocks, atomics into stats ----
__global__ __launch_bounds__(256) void gn_part_k(const float* __restrict__ x,
                                                 float* __restrict__ stats) {
    const int bg = blockIdx.x >> 2, part = blockIdx.x & 3;
    const float4* base = (const float4*)(x + (size_t)bg * 32768 + part * 8192);
    float s = 0.f, ss = 0.f;
    for (int i = threadIdx.x; i < 2048; i += 256) {
        float4 v = base[i];
        s  += v.x + v.y + v.z + v.w;
        ss += v.x*v.x + v.y*v.y + v.z*v.z + v.w*v.w;
    }
    #pragma unroll
    for (int o = 32; o; o >>= 1) { s += __shfl_xor(s, o); ss += __shfl_xor(ss, o); }
    if ((threadIdx.x & 63) == 0) {
        atomicAdd(&stats[bg * 2],     s);
        atomicAdd(&stats[bg * 2 + 1], ss);
    }
}

// ------- GN apply + transpose: write hT[b][n][c] bf16 (64x64 tiles) ---------
__global__ __launch_bounds__(256) void gn_apply_t_k(const float* __restrict__ x,
        const float* __restrict__ stats, const float* __restrict__ sc,
        const float* __restrict__ bi, ushort* __restrict__ hT) {
    const int n0 = blockIdx.x * 64, c0 = blockIdx.y * 64, b = blockIdx.z;
    __shared__ ushort tile[64][65];
    const int t = threadIdx.x;
    #pragma unroll
    for (int it = 0; it < 4; ++it) {
        const int r = (t >> 4) + it * 16, col4 = t & 15;
        const int c = c0 + r, bg = b * 32 + (c >> 3);
        const float S = stats[bg * 2], SS = stats[bg * 2 + 1];
        const float mean = S * (1.f / 32768.f);
        const float var  = SS * (1.f / 32768.f) - mean * mean;
        const float a  = rsqrtf(var + 1e-6f) * sc[c];
        const float bb = bi[c] - mean * a;
        float4 v = *(const float4*)(x + ((size_t)(b * 256 + c)) * 4096 + n0 + col4 * 4);
        tile[r][col4*4 + 0] = f2bf(v.x * a + bb);
        tile[r][col4*4 + 1] = f2bf(v.y * a + bb);
        tile[r][col4*4 + 2] = f2bf(v.z * a + bb);
        tile[r][col4*4 + 3] = f2bf(v.w * a + bb);
    }
    __syncthreads();
    #pragma unroll
    for (int it = 0; it < 2; ++it) {
        const int nr = (t >> 3) + it * 32, c8 = t & 7;
        uint4 st;
        ushort e0 = tile[c8*8+0][nr], e1 = tile[c8*8+1][nr];
        ushort e2 = tile[c8*8+2][nr], e3 = tile[c8*8+3][nr];
        ushort e4 = tile[c8*8+4][nr], e5 = tile[c8*8+5][nr];
        ushort e6 = tile[c8*8+6][nr], e7 = tile[c8*8+7][nr];
        st.x = (uint)e0 | ((uint)e1 << 16);
        st.y = (uint)e2 | ((uint)e3 << 16);
        st.z = (uint)e4 | ((uint)e5 << 16);
        st.w = (uint)e6 | ((uint)e7 << 16);
        *(uint4*)(hT + ((size_t)b * 4096 + n0 + nr) * 256 + c0 + c8 * 8) = st;
    }
}

// ---------------- Weight prep: bf16 casts, wo column-permute, bias pack -----
__global__ __launch_bounds__(256) void wprep_k(
        const float* __restrict__ wq, const float* __restrict__ wk,
        const float* __restrict__ wv, const float* __restrict__ wo,
        const float* __restrict__ bq, const float* __restrict__ bk,
        const float* __restrict__ bv,
        ushort* __restrict__ wqkv, ushort* __restrict__ wo_p,
        float* __restrict__ bqkv) {
    const int i = blockIdx.x * 256 + threadIdx.x;
    if (i < 196608) {               // wqkv[768][256]
        const int o = i >> 8, k = i & 255;
        const float* W = (o < 256) ? wq : ((o < 512) ? wk : wv);
        wqkv[i] = f2bf(W[(o & 255) * 256 + k]);
    } else if (i < 262144) {        // wo_p[o][h*64+d] = wo[o][d*4+h]
        const int j = i - 196608;
        const int o = j >> 8, kp = j & 255;
        const int h = kp >> 6, d = kp & 63;
        wo_p[j] = f2bf(wo[o * 256 + d * 4 + h]);
    } else if (i < 262912) {        // bqkv[768]
        const int o = i - 262144;
        bqkv[o] = (o < 256) ? bq[o] : ((o < 512) ? bk[o - 256] : bv[o - 512]);
    }
}

// ---------------- QKV GEMM (MFMA bf16): 128x64 tiles, grid (64,6,2) ---------
// Q rows written as f32 to qf; K/V rows as bf16 to kvb.
__global__ __launch_bounds__(256) void qkv_gemm_k(
        const ushort* __restrict__ Wqkv, const float* __restrict__ bqkv,
        const ushort* __restrict__ hT, float* __restrict__ qf,
        ushort* __restrict__ kvb) {
    const int nt = blockIdx.x, mt = blockIdx.y, b = blockIdx.z;
    __shared__ ushort As[128 * LSTR];
    __shared__ ushort Bs[64 * LSTR];
    const int t = threadIdx.x;
    const int wave = t >> 6, ln = t & 63;
    const int wm = wave >> 1, wn = wave & 1;
    f32x4 acc[4][2] = {};
    const ushort* Ag = Wqkv + (size_t)(mt * 128) * 256;
    const ushort* Bg = hT + ((size_t)b * 4096 + nt * 64) * 256;
    const int srow = t >> 2, sc8 = (t & 3) * 8;
    const int fr = ln & 15, kA = (ln >> 4) * 8;

    for (int k0 = 0; k0 < 256; k0 += 32) {
        *(uint4*)&As[srow * LSTR + sc8]        = *(const uint4*)&Ag[(size_t)srow * 256 + k0 + sc8];
        *(uint4*)&As[(srow + 64) * LSTR + sc8] = *(const uint4*)&Ag[(size_t)(srow + 64) * 256 + k0 + sc8];
        *(uint4*)&Bs[srow * LSTR + sc8]        = *(const uint4*)&Bg[(size_t)srow * 256 + k0 + sc8];
        __syncthreads();
        bf16x8 af[4], bfr[2];
        #pragma unroll
        for (int m = 0; m < 4; ++m) af[m]  = *(bf16x8*)&As[(wm * 64 + m * 16 + fr) * LSTR + kA];
        #pragma unroll
        for (int n = 0; n < 2; ++n) bfr[n] = *(bf16x8*)&Bs[(wn * 32 + n * 16 + fr) * LSTR + kA];
        #pragma unroll
        for (int m = 0; m < 4; ++m)
            #pragma unroll
            for (int n = 0; n < 2; ++n)
                acc[m][n] = __builtin_amdgcn_mfma_f32_16x16x32_bf16(af[m], bfr[n], acc[m][n], 0, 0, 0);
        __syncthreads();
    }
    const int colb = nt * 64 + wn * 32 + fr;
    const int rowb = mt * 128 + wm * 64;
    #pragma unroll
    for (int m = 0; m < 4; ++m) {
        const int o0 = rowb + m * 16 + ((ln >> 4) << 2);
        const int proj = o0 >> 8;          // wave-uniform (64-chunk within one proj)
        const int head = (o0 >> 6) & 3;
        const int d0 = o0 & 63;
        const float4 bi4 = *(const float4*)&bqkv[o0];
        if (proj == 0) {
            float* obase = qf + ((size_t)(b * 4 + head) * 4096) * 64 + d0;
            #pragma unroll
            for (int n = 0; n < 2; ++n) {
                const int nn = colb + n * 16;
                f32x4 a = acc[m][n];
                float4 st = { a[0] + bi4.x, a[1] + bi4.y, a[2] + bi4.z, a[3] + bi4.w };
                *(float4*)&obase[(size_t)nn * 64] = st;
            }
        } else {
            ushort* obase = kvb + ((size_t)(proj - 1) * 8 + (b * 4 + head)) * (4096 * 64) + d0;
            #pragma unroll
            for (int n = 0; n < 2; ++n) {
                const int nn = colb + n * 16;
                f32x4 a = acc[m][n];
                uint2 st;
                st.x = (uint)f2bf(a[0] + bi4.x) | ((uint)f2bf(a[1] + bi4.y) << 16);
                st.y = (uint)f2bf(a[2] + bi4.z) | ((uint)f2bf(a[3] + bi4.w) << 16);
                *(uint2*)&obase[(size_t)nn * 64] = st;
            }
        }
    }
}

// ------ Attention: SGPR q (uniform loads), LDS same-address broadcast PV ----
__global__ __launch_bounds__(256) void attn_k(
        const float* __restrict__ qf, const ushort* __restrict__ kb,
        const ushort* __restrict__ vb, const int* __restrict__ aidx,
        const int* __restrict__ vmask, ushort* __restrict__ attnb) {
    const int bh = blockIdx.x & 7;       // XCD-affinity
    const int q4 = blockIdx.x >> 3;
    const int wave = threadIdx.x >> 6, ln = threadIdx.x & 63;
    const int n = q4 * 4 + wave;
    const ushort* kbase = kb + (size_t)bh * (4096 * 64);
    const ushort* vbase = vb + (size_t)bh * (4096 * 64);
    const int idx = aidx[n * 64 + ln];
    const int msk = vmask[n * 64 + ln];

    // wave-uniform q pointer -> scalar/uniform loads, no per-element readlane
    const int nu = __builtin_amdgcn_readfirstlane(n);
    const float4* __restrict__ qrow4 =
        (const float4*)(qf + ((size_t)bh * 4096 + nu) * 64);

    // --- QK: lane ln owns neighbor ln; q components are wave-uniform --------
    const uint4* krow = (const uint4*)(kbase + (size_t)idx * 64);
    float d0 = 0.f, d1 = 0.f, d2 = 0.f, d3 = 0.f;
    #pragma unroll
    for (int c = 0; c < 8; ++c) {
        uint4 u = krow[c];
        float4 qa = qrow4[c * 2];
        float4 qb = qrow4[c * 2 + 1];
        d0 += __uint_as_float(u.x << 16)         * qa.x;
        d1 += __uint_as_float(u.x & 0xffff0000u) * qa.y;
        d2 += __uint_as_float(u.y << 16)         * qa.z;
        d3 += __uint_as_float(u.y & 0xffff0000u) * qa.w;
        d0 += __uint_as_float(u.z << 16)         * qb.x;
        d1 += __uint_as_float(u.z & 0xffff0000u) * qb.y;
        d2 += __uint_as_float(u.w << 16)         * qb.z;
        d3 += __uint_as_float(u.w & 0xffff0000u) * qb.w;
    }
    const float dot = (d0 + d1) + (d2 + d3);
    float mx = msk ? dot : -1e30f;
    #pragma unroll
    for (int o = 32; o; o >>= 1) mx = fmaxf(mx, __shfl_xor(mx, o));
    const float e = msk ? __expf(dot - mx) : 0.f;
    float s = e;
    #pragma unroll
    for (int o = 32; o; o >>= 1) s += __shfl_xor(s, o);
    const float wgt = e / s;

    // --- PV: (idx*128, wgt) pairs in LDS; ds_read_b64 broadcast per iter ----
    __shared__ uint2 pw[4][64];
    pw[wave][ln] = make_uint2((uint)idx << 7, __float_as_uint(wgt));  // 128 B/row

    const int p = ln >> 4, d4 = ln & 15;
    const uint2* pwp = &pw[wave][p];             // lane reads pair k+p
    const char* vb2 = (const char*)(vbase + d4 * 4);
    float a0 = 0.f, a1 = 0.f, a2 = 0.f, a3 = 0.f;
    #pragma unroll
    for (int k = 0; k < 64; k += 4) {
        const uint2 iw = pwp[k];                 // ds_read_b64, same-addr bcast
        const uint2 u = *(const uint2*)(vb2 + iw.x);
        const float sw = __uint_as_float(iw.y);
        a0 += sw * __uint_as_float(u.x << 16);
        a1 += sw * __uint_as_float(u.x & 0xffff0000u);
        a2 += sw * __uint_as_float(u.y << 16);
        a3 += sw * __uint_as_float(u.y & 0xffff0000u);
    }
    #pragma unroll
    for (int o = 16; o <= 32; o <<= 1) {
        a0 += __shfl_xor(a0, o); a1 += __shfl_xor(a1, o);
        a2 += __shfl_xor(a2, o); a3 += __shfl_xor(a3, o);
    }
    if (p == 0) {
        const int b = bh >> 2, h = bh & 3;
        uint2 st;
        st.x = (uint)f2bf(a0) | ((uint)f2bf(a1) << 16);
        st.y = (uint)f2bf(a2) | ((uint)f2bf(a3) << 16);
        *(uint2*)(attnb + ((size_t)b * 4096 + n) * 256 + h * 64 + d4 * 4) = st;
    }
}

// ---------------- Output GEMM (MFMA): 64x64 tiles, grid (64,4,2) ------------
__global__ __launch_bounds__(256) void out_gemm_k(
        const ushort* __restrict__ wo_p, const float* __restrict__ bo,
        const ushort* __restrict__ attnb, const float* __restrict__ x,
        float* __restrict__ outp) {
    const int nt = blockIdx.x, mt = blockIdx.y, b = blockIdx.z;
    __shared__ ushort As[64 * LSTR];
    __shared__ ushort Bs[64 * LSTR];
    const int t = threadIdx.x;
    const int wave = t >> 6, ln = t & 63;
    const int wm = wave >> 1, wn = wave & 1;
    f32x4 acc[2][2] = {};
    const ushort* Ag = wo_p + (size_t)(mt * 64) * 256;
    const ushort* Bg = attnb + ((size_t)b * 4096 + nt * 64) * 256;
    const int srow = t >> 2, sc8 = (t & 3) * 8;
    const int fr = ln & 15, kA = (ln >> 4) * 8;

    for (int k0 = 0; k0 < 256; k0 += 32) {
        *(uint4*)&As[srow * LSTR + sc8] = *(const uint4*)&Ag[(size_t)srow * 256 + k0 + sc8];
        *(uint4*)&Bs[srow * LSTR + sc8] = *(const uint4*)&Bg[(size_t)srow * 256 + k0 + sc8];
        __syncthreads();
        bf16x8 af[2], bfr[2];
        #pragma unroll
        for (int m = 0; m < 2; ++m) af[m]  = *(bf16x8*)&As[(wm * 32 + m * 16 + fr) * LSTR + kA];
        #pragma unroll
        for (int n = 0; n < 2; ++n) bfr[n] = *(bf16x8*)&Bs[(wn * 32 + n * 16 + fr) * LSTR + kA];
        #pragma unroll
        for (int m = 0; m < 2; ++m)
            #pragma unroll
            for (int n = 0; n < 2; ++n)
                acc[m][n] = __builtin_amdgcn_mfma_f32_16x16x32_bf16(af[m], bfr[n], acc[m][n], 0, 0, 0);
        __syncthreads();
    }
    const int colb = nt * 64 + wn * 32 + fr;
    const int rowb = mt * 64 + wm * 32;
    #pragma unroll
    for (int m = 0; m < 2; ++m) {
        const int o0 = rowb + m * 16 + ((ln >> 4) << 2);
        const float4 bi4 = *(const float4*)&bo[o0];
        const float* bip = (const float*)&bi4;
        #pragma unroll
        for (int n = 0; n < 2; ++n) {
            const int nn = colb + n * 16;
            #pragma unroll
            for (int r = 0; r < 4; ++r) {
                const size_t a = ((size_t)(b * 256 + o0 + r)) * 4096 + nn;
                outp[a] = acc[m][n][r] + bip[r] + x[a];
            }
        }
    }
}

extern "C" void kernel_launch(void* const* d_in, const int* in_sizes, int n_in,
                              void* d_out, int out_size, void* d_ws, size_t ws_size,
                              hipStream_t stream) {
    const float* x     = (const float*)d_in[0];
    const int*   vmask = (const int*)d_in[1];
    const int*   aidx  = (const int*)d_in[2];
    const float* gsc   = (const float*)d_in[3];
    const float* gbi   = (const float*)d_in[4];
    const float* wq    = (const float*)d_in[5];
    const float* bq    = (const float*)d_in[6];
    const float* wk    = (const float*)d_in[7];
    const float* bk    = (const float*)d_in[8];
    const float* wv    = (const float*)d_in[9];
    const float* bv    = (const float*)d_in[10];
    const float* wo    = (const float*)d_in[11];
    const float* bo    = (const float*)d_in[12];
    float* outp = (float*)d_out;

    char* w = (char*)d_ws;
    float*  stats = (float*)w;                          // 512 B (pad 1024)
    ushort* wqkv  = (ushort*)(w + 1024);                // 393216 B
    ushort* wo_p  = (ushort*)(w + 394240);              // 131072 B
    float*  bqkv  = (float*)(w + 525312);               // 3072 B
    ushort* hT    = (ushort*)(w + 528384);              // 4 MB
    float*  qf    = (float*)(w + 4722688);              // 8 MB f32 Q
    ushort* kvb   = (ushort*)(w + 13111296);            // 8 MB (K,V bf16)
    ushort* attnb = (ushort*)(w + 21499904);            // 4 MB

    ushort* kbuf = kvb;
    ushort* vbuf = kvb + 2097152;

    hipMemsetAsync(stats, 0, 512, stream);
    hipLaunchKernelGGL(gn_part_k,    dim3(256),        dim3(256), 0, stream, x, stats);
    hipLaunchKernelGGL(wprep_k,      dim3(1027),       dim3(256), 0, stream,
                       wq, wk, wv, wo, bq, bk, bv, wqkv, wo_p, bqkv);
    hipLaunchKernelGGL(gn_apply_t_k, dim3(64, 4, 2),   dim3(256), 0, stream,
                       x, stats, gsc, gbi, hT);
    hipLaunchKernelGGL(qkv_gemm_k,   dim3(64, 6, 2),   dim3(256), 0, stream,
                       wqkv, bqkv, hT, qf, kvb);
    hipLaunchKernelGGL(attn_k,       dim3(8192),       dim3(256), 0, stream,
                       qf, kbuf, vbuf, aidx, vmask, attnb);
    hipLaunchKernelGGL(out_gemm_k,   dim3(64, 4, 2),   dim3(256), 0, stream,
                       wo_p, bo, attnb, x, outp);
}